// Round 5
// baseline (314.045 us; speedup 1.0000x reference)
//
#include <hip/hip_runtime.h>
#include <hip/hip_bf16.h>

#define DHID 64
typedef __attribute__((ext_vector_type(8))) short short8;
typedef __attribute__((ext_vector_type(4))) float f32x4;

static __device__ __forceinline__ short tobf(float f) {
  __hip_bfloat16 h = __float2bfloat16(f);
  return *reinterpret_cast<short*>(&h);
}
static __device__ __forceinline__ float frombf(short s) {
  union { unsigned u; float f; } v; v.u = ((unsigned)(unsigned short)s) << 16; return v.f;
}

// ---------- CSR build ----------
__global__ void k_init(int* __restrict__ cnt, int* __restrict__ fill,
                       int* __restrict__ bcnt, int n) {
  int i = blockIdx.x * blockDim.x + threadIdx.x;
  if (i < n) { cnt[i] = 1; fill[i] = 0; }  // cnt=1 pre-counts the self-loop
  if (i < 8) bcnt[i] = 0;
}

// one-pass 8-way partition of edges by dst window (block-local LDS histogram,
// one global atomic per window per block). Buckets live in the xb/hb region
// (dead until after CSR build).
__global__ void k_bucket(const int* __restrict__ src, const int* __restrict__ dst,
                         int2* __restrict__ bkt, int* __restrict__ bcnt,
                         int E, int N, int cap) {
  __shared__ int lcnt[8];
  __shared__ int lbase[8];
  int tid = threadIdx.x;
  int c0 = blockIdx.x * 2048;
  if (c0 >= E) return;
  if (tid < 8) lcnt[tid] = 0;
  __syncthreads();
  float inv = 8.0f / (float)N;
  int wloc[8], dloc[8], sloc[8];
  #pragma unroll
  for (int k = 0; k < 8; k++) {
    int i = c0 + tid + k * 256;
    if (i < E) {
      int d = dst[i];
      int w = min(7, (int)((float)d * inv));
      wloc[k] = w; dloc[k] = d; sloc[k] = src[i];
      atomicAdd(&lcnt[w], 1);
    } else wloc[k] = -1;
  }
  __syncthreads();
  if (tid < 8) lbase[tid] = atomicAdd(&bcnt[tid], lcnt[tid]);
  __syncthreads();
  if (tid < 8) lcnt[tid] = 0;  // reuse as local rank counter
  __syncthreads();
  #pragma unroll
  for (int k = 0; k < 8; k++) {
    int w = wloc[k];
    if (w >= 0) {
      int r = atomicAdd(&lcnt[w], 1);
      bkt[(size_t)w * cap + lbase[w] + r] = make_int2(sloc[k], dloc[k]);
    }
  }
}

// window w's blocks (blockIdx%8==w, XCD-aligned round-robin) read ONLY bucket w
__global__ void k_hist2(const int2* __restrict__ bkt, const int* __restrict__ bcnt,
                        int* __restrict__ cnt, int cap) {
  int w = blockIdx.x & 7, bi = blockIdx.x >> 3, nb = gridDim.x >> 3;
  int n = bcnt[w];
  const int2* b = bkt + (size_t)w * cap;
  for (int i = bi * blockDim.x + threadIdx.x; i < n; i += nb * blockDim.x)
    atomicAdd(&cnt[b[i].y], 1);
}

__global__ void k_scan_block(int* __restrict__ buf, int n, int* __restrict__ bsum) {
  __shared__ int lds[256];
  int tid = threadIdx.x;
  int base = blockIdx.x * 1024 + tid * 4;
  int a0 = (base + 0) < n ? buf[base + 0] : 0;
  int a1 = (base + 1) < n ? buf[base + 1] : 0;
  int a2 = (base + 2) < n ? buf[base + 2] : 0;
  int a3 = (base + 3) < n ? buf[base + 3] : 0;
  int s = a0 + a1 + a2 + a3;
  lds[tid] = s; __syncthreads();
  for (int off = 1; off < 256; off <<= 1) {
    int t = (tid >= off) ? lds[tid - off] : 0;
    __syncthreads();
    lds[tid] += t;
    __syncthreads();
  }
  int excl = lds[tid] - s;
  if ((base + 0) < n) buf[base + 0] = excl; excl += a0;
  if ((base + 1) < n) buf[base + 1] = excl; excl += a1;
  if ((base + 2) < n) buf[base + 2] = excl; excl += a2;
  if ((base + 3) < n) buf[base + 3] = excl;
  if (tid == 255) bsum[blockIdx.x] = lds[255];
}

__global__ void k_scan_mid(int* __restrict__ bsum, int nb) {
  int lane = threadIdx.x;
  int v0 = (lane < nb) ? bsum[lane] : 0;
  #pragma unroll
  for (int off = 1; off < 64; off <<= 1) { int t = __shfl_up(v0, off, 64); if (lane >= off) v0 += t; }
  int v1 = (64 + lane) < nb ? bsum[64 + lane] : 0;
  #pragma unroll
  for (int off = 1; off < 64; off <<= 1) { int t = __shfl_up(v1, off, 64); if (lane >= off) v1 += t; }
  v1 += __shfl(v0, 63, 64);
  if (lane < nb) bsum[lane] = v0;
  if ((64 + lane) < nb) bsum[64 + lane] = v1;
}

__global__ void k_scan_add(int* __restrict__ buf, int n, const int* __restrict__ bsum, int nb) {
  int i = blockIdx.x * blockDim.x + threadIdx.x;
  if (i < n) { int c = i >> 10; if (c > 0) buf[i] += bsum[c - 1]; }
  if (i == 0) buf[n] = bsum[nb - 1];
}

// deterministic self-loop placement: reserved last slot of each row
__global__ void k_self(const int* __restrict__ roff, int* __restrict__ csr, int N) {
  int i = blockIdx.x * blockDim.x + threadIdx.x;
  if (i < N) csr[roff[i + 1] - 1] = i;
}

__global__ void k_fill2(const int2* __restrict__ bkt, const int* __restrict__ bcnt,
                        const int* __restrict__ roff, int* __restrict__ fill,
                        int* __restrict__ csr, int cap) {
  int w = blockIdx.x & 7, bi = blockIdx.x >> 3, nb = gridDim.x >> 3;
  int n = bcnt[w];
  const int2* b = bkt + (size_t)w * cap;
  for (int i = bi * blockDim.x + threadIdx.x; i < n; i += nb * blockDim.x) {
    int2 e = b[i];
    int pos = roff[e.y] + atomicAdd(&fill[e.y], 1);
    csr[pos] = e.x;
  }
}

// ---------- prep: x fp32 -> bf16, XOR-swizzled rows (K=128) ----------
__global__ void k_cvt(const float* __restrict__ x, short* __restrict__ xb, int N) {
  int i = blockIdx.x * blockDim.x + threadIdx.x;   // one 8-elem chunk
  int tot = N * 16;
  if (i >= tot) return;
  int row = i >> 4;
  int kc = (i & 15) << 3;
  const float4* xp = (const float4*)(x + (size_t)row * 128 + kc);
  float4 v0 = xp[0], v1 = xp[1];
  short8 o;
  o[0] = tobf(v0.x); o[1] = tobf(v0.y); o[2] = tobf(v0.z); o[3] = tobf(v0.w);
  o[4] = tobf(v1.x); o[5] = tobf(v1.y); o[6] = tobf(v1.z); o[7] = tobf(v1.w);
  int ks = kc ^ ((row & 7) << 3);
  *(short8*)(xb + (size_t)row * 128 + ks) = o;
}

// ---------- prep: W [K][64] -> Wt bf16 [64][K], XOR-swizzled ----------
__global__ void k_prep(const float* __restrict__ W, short* __restrict__ wt, int K) {
  for (int e = threadIdx.x; e < 64 * K; e += blockDim.x) {
    int c = e / K, k = e - c * K;
    wt[c * K + (k ^ ((c & 7) << 3))] = tobf(W[k * 64 + c]);
  }
}

// ---------- MFMA gemm: hb[n][d] = xb[n][:] @ Wt[d][:]^T ; + as/ad dots ----------
template<int K>
__launch_bounds__(256)
__global__ void k_mgemm(const short* __restrict__ xb, const short* __restrict__ wt,
                        const float* __restrict__ a_s, const float* __restrict__ a_d,
                        short* __restrict__ hb, float* __restrict__ asb,
                        float* __restrict__ adb, int N) {
  constexpr int ASZ = 64 * K * 2;          // bytes of A tile (== B tile)
  __shared__ __align__(16) short lds[2 * 64 * K];
  int tid = threadIdx.x;
  int n0 = blockIdx.x * 64;

  const char* ga = (const char*)xb + (size_t)n0 * (K * 2);
  const char* gb = (const char*)wt;
  #pragma unroll
  for (int j = 0; j < (2 * ASZ) / 4096; j++) {
    int d = j * 4096 + tid * 16;
    const char* src = (d < ASZ) ? (ga + d) : (gb + (d - ASZ));
    __builtin_amdgcn_global_load_lds(
        (__attribute__((address_space(1))) const void*)src,
        (__attribute__((address_space(3))) void*)((char*)lds + d), 16, 0, 0);
  }
  __syncthreads();

  int l = tid & 63, w = tid >> 6;
  int c = l & 15, g = l >> 4;
  const short* A = lds;
  const short* B = lds + 64 * K;
  f32x4 acc[4];
  #pragma unroll
  for (int t = 0; t < 4; t++) acc[t] = (f32x4){0.f, 0.f, 0.f, 0.f};

  int arow = 16 * w + c;
  #pragma unroll
  for (int s = 0; s < K / 32; s++) {
    int ke = s * 32 + g * 8;
    short8 af = *(const short8*)(A + arow * K + (ke ^ ((arow & 7) << 3)));
    #pragma unroll
    for (int t = 0; t < 4; t++) {
      int bcol = 16 * t + c;
      short8 bf = *(const short8*)(B + bcol * K + (ke ^ ((bcol & 7) << 3)));
      acc[t] = __builtin_amdgcn_mfma_f32_16x16x32_bf16(af, bf, acc[t], 0, 0, 0);
    }
  }

  float av_s[4], av_d[4];
  #pragma unroll
  for (int t = 0; t < 4; t++) { av_s[t] = a_s[16 * t + c]; av_d[t] = a_d[16 * t + c]; }
  #pragma unroll
  for (int q = 0; q < 4; q++) {
    int row = n0 + 16 * w + g * 4 + q;
    bool ok = row < N;
    float rs = 0.f, rd = 0.f;
    #pragma unroll
    for (int t = 0; t < 4; t++) {
      float v = acc[t][q];
      if (ok) hb[(size_t)row * 64 + 16 * t + c] = tobf(v);
      rs += v * av_s[t]; rd += v * av_d[t];
    }
    #pragma unroll
    for (int off = 1; off < 16; off <<= 1) {
      rs += __shfl_xor(rs, off, 64);
      rd += __shfl_xor(rd, off, 64);
    }
    if (ok && c == 0) { asb[row] = rs; adb[row] = rd; }
  }
}

// ---------- sparse: fused softmax + aggregation, one wave per dst node ----------
__global__ void k_agg(const int* __restrict__ roff, const int* __restrict__ csr,
                      const float* __restrict__ asb, const float* __restrict__ adb,
                      const short* __restrict__ hb, const float* __restrict__ b,
                      float* __restrict__ out, short* __restrict__ outb,
                      int N, int relu) {
  int lane = threadIdx.x & 63;
  int wid = blockIdx.x * (blockDim.x >> 6) + (threadIdx.x >> 6);
  int nw = gridDim.x * (blockDim.x >> 6);
  float bv = b[lane];
  for (int n = wid; n < N; n += nw) {
    int r0 = roff[n], r1 = roff[n + 1];
    float adn = adb[n];
    float acc = 0.f, denl = 0.f;
    for (int base = r0; base < r1; base += 64) {
      int cnt = min(64, r1 - base);
      int s = 0; float e = 0.f;
      if (lane < cnt) {
        s = csr[base + lane];
        float l = asb[s] + adn;
        l = fmaxf(l, 0.2f * l);
        e = __expf(l);
      }
      denl += e;
      for (int j = 0; j < cnt; j += 8) {
        #pragma unroll
        for (int k = 0; k < 8; k++) {
          int   sk = __builtin_amdgcn_readlane(s, j + k);
          float ek = __uint_as_float(__builtin_amdgcn_readlane(__float_as_uint(e), j + k));
          acc += ek * frombf(hb[(size_t)sk * DHID + lane]);
        }
      }
    }
    float den = denl;
    #pragma unroll
    for (int off = 32; off; off >>= 1) den += __shfl_xor(den, off, 64);
    float o = acc / (den + 1e-16f) + bv;
    if (relu) o = fmaxf(o, 0.f);
    out[(size_t)n * DHID + lane] = o;
    if (outb) outb[(size_t)n * DHID + (lane ^ ((n & 7) << 3))] = tobf(o);
  }
}

extern "C" void kernel_launch(void* const* d_in, const int* in_sizes, int n_in,
                              void* d_out, int out_size, void* d_ws, size_t ws_size,
                              hipStream_t stream) {
  const float* x   = (const float*)d_in[0];
  const int*   ei  = (const int*)d_in[1];
  const float* W1  = (const float*)d_in[2];
  const float* as1 = (const float*)d_in[3];
  const float* ad1 = (const float*)d_in[4];
  const float* b1  = (const float*)d_in[5];
  const float* W2  = (const float*)d_in[6];
  const float* as2 = (const float*)d_in[7];
  const float* ad2 = (const float*)d_in[8];
  const float* b2  = (const float*)d_in[9];

  int N = in_sizes[0] / 128;
  int E = in_sizes[1] / 2;
  const int* srcp = ei;
  const int* dstp = ei + E;

  float* emb  = (float*)d_out;
  float* out2 = emb + (size_t)N * DHID;

  char* w = (char*)d_ws;
  auto alloc = [&](size_t bytes) { char* p = w; w += (bytes + 255) & ~(size_t)255; return p; };
  int NR = ((N + 63) / 64) * 64;
  int* roff = (int*)alloc((size_t)(N + 1) * 4);
  int* fill = (int*)alloc((size_t)N * 4);
  int* csr  = (int*)alloc((size_t)(E + N) * 4);
  int* bsum = (int*)alloc(2048);
  short* xb = (short*)alloc((size_t)NR * 128 * 2);
  short* hb = (short*)alloc((size_t)NR * 64 * 2);
  float* asb = (float*)alloc((size_t)N * 4);
  float* adb = (float*)alloc((size_t)N * 4);
  short* wt1 = (short*)alloc(64 * 128 * 2);
  short* wt2 = (short*)alloc(64 * 64 * 2);
  short* eb = xb;                 // overlay: xb dead after mgemm1
  int2* bkt = (int2*)xb;          // overlay: buckets dead before k_cvt writes xb
  int* bcnt = (int*)hb;           // overlay: hb dead until mgemm1
  int cap = E / 8 + 65536;

  int nb = (N + 1023) / 1024;
  int NBLK = (N + 63) / 64;

  k_init<<<(N + 255) / 256, 256, 0, stream>>>(roff, fill, bcnt, N);
  k_bucket<<<(E + 2047) / 2048, 256, 0, stream>>>(srcp, dstp, bkt, bcnt, E, N, cap);
  k_hist2<<<1024, 256, 0, stream>>>(bkt, bcnt, roff, cap);
  k_scan_block<<<nb, 256, 0, stream>>>(roff, N, bsum);
  k_scan_mid<<<1, 64, 0, stream>>>(bsum, nb);
  k_scan_add<<<(N + 255) / 256, 256, 0, stream>>>(roff, N, bsum, nb);
  k_self<<<(N + 255) / 256, 256, 0, stream>>>(roff, csr, N);
  k_fill2<<<1024, 256, 0, stream>>>(bkt, bcnt, roff, fill, csr, cap);

  // buckets now dead -> safe to overwrite xb/hb
  k_prep<<<1, 256, 0, stream>>>(W1, wt1, 128);
  k_prep<<<1, 256, 0, stream>>>(W2, wt2, 64);
  k_cvt<<<(N * 16 + 255) / 256, 256, 0, stream>>>(x, xb, N);

  k_mgemm<128><<<NBLK, 256, 0, stream>>>(xb, wt1, as1, ad1, hb, asb, adb, N);
  k_agg<<<2048, 256, 0, stream>>>(roff, csr, asb, adb, hb, b1, emb, eb, N, 1);
  k_mgemm<64><<<NBLK, 256, 0, stream>>>(eb, wt2, as2, ad2, hb, asb, adb, N);
  k_agg<<<2048, 256, 0, stream>>>(roff, csr, asb, adb, hb, b2, out2, (short*)nullptr, N, 0);
}